// Round 4
// baseline (166.451 us; speedup 1.0000x reference)
//
#include <hip/hip_runtime.h>
#include <math.h>

#define Bsz 1024
#define Dd  256
#define Hh  512
#define NOUT 8192       // D*K, K=32

typedef __attribute__((ext_vector_type(8))) short bf8_t;   // 8 bf16 (4 VGPRs)
typedef __attribute__((ext_vector_type(4))) float f4_t;    // 4 fp32

__device__ inline ushort f2b(float f) {
  union { float f; unsigned u; } c; c.f = f;
  unsigned r = c.u + 0x7fffu + ((c.u >> 16) & 1u);   // RNE
  return (ushort)(r >> 16);
}

__device__ inline void async16(const ushort* g, ushort* l) {
  __builtin_amdgcn_global_load_lds((const __attribute__((address_space(1))) void*)g,
                                   (__attribute__((address_space(3))) void*)l, 16, 0, 0);
}

__device__ inline int mod255(int v) {   // valid for v in [0, 765)
  if (v >= 510) return v - 510;
  if (v >= 255) return v - 255;
  return v;
}

// ---------- prep: fp32 -> bf16 (+mask) for x, W0, W1, W2, Wout; +lpa; +bar zero --------
// blocks: [0,128) x | [128,192) W0 | [192,320) W1 | [320,448) W2 | [448,2496) Wout
// block 2496: lpa = log_softmax(ulpa) and zero the grid-barrier counters.
__global__ __launch_bounds__(256) void prep(
    const float* __restrict__ x,  const float* __restrict__ W0,
    const float* __restrict__ W1, const float* __restrict__ W2,
    const float* __restrict__ Wout, const float* __restrict__ ulpa,
    ushort* __restrict__ xb, ushort* __restrict__ w0b, ushort* __restrict__ w1b,
    ushort* __restrict__ w2b, ushort* __restrict__ woutb,
    float* __restrict__ lpa, unsigned* __restrict__ bar)
{
  const int blk = blockIdx.x, tid = threadIdx.x;
  if (blk == 2496) {
    if (tid < 16) bar[tid] = 0u;
    if (tid < Dd - 1) {
      float v0 = ulpa[tid * 4 + 0], v1 = ulpa[tid * 4 + 1];
      float v2 = ulpa[tid * 4 + 2], v3 = ulpa[tid * 4 + 3];
      float m = fmaxf(fmaxf(v0, v1), fmaxf(v2, v3));
      float s = __expf(v0 - m) + __expf(v1 - m) + __expf(v2 - m) + __expf(v3 - m);
      float l = m + __logf(s);
      lpa[tid * 4 + 0] = v0 - l;
      lpa[tid * 4 + 1] = v1 - l;
      lpa[tid * 4 + 2] = v2 - l;
      lpa[tid * 4 + 3] = v3 - l;
    }
    return;
  }
  const float* src; ushort* dst; int lb, mode;
  if (blk < 128)      { src = x;    dst = xb;    lb = blk;       mode = 0; }
  else if (blk < 192) { src = W0;   dst = w0b;   lb = blk - 128; mode = 1; }
  else if (blk < 320) { src = W1;   dst = w1b;   lb = blk - 192; mode = 2; }
  else if (blk < 448) { src = W2;   dst = w2b;   lb = blk - 320; mode = 2; }
  else                { src = Wout; dst = woutb; lb = blk - 448; mode = 3; }

  const int e = lb * 2048 + tid * 8;
  float4 v0 = *(const float4*)(src + e);
  float4 v1 = *(const float4*)(src + e + 4);
  float vv[8] = {v0.x, v0.y, v0.z, v0.w, v1.x, v1.y, v1.z, v1.w};
  ushort u[8];
  if (mode == 0) {
#pragma unroll
    for (int i = 0; i < 8; i++) u[i] = f2b(vv[i]);
  } else if (mode == 1) {            // Kd=256: (n%255) >= k
    int n = e >> 8, k0 = e & 255, nd = mod255(n);
#pragma unroll
    for (int i = 0; i < 8; i++) u[i] = (nd >= k0 + i) ? f2b(vv[i]) : (ushort)0;
  } else if (mode == 2) {            // Kd=512: (n%255) >= (k%255)
    int n = e >> 9, k0 = e & 511, nd = mod255(n);
#pragma unroll
    for (int i = 0; i < 8; i++) u[i] = (nd >= mod255(k0 + i)) ? f2b(vv[i]) : (ushort)0;
  } else {                           // Kd=512: (n>>5)-1 >= (k%255)
    int n = e >> 9, k0 = e & 511, nd = (n >> 5) - 1;
#pragma unroll
    for (int i = 0; i < 8; i++) u[i] = (nd >= mod255(k0 + i)) ? f2b(vv[i]) : (ushort)0;
  }
  *(ushort4*)(dst + e)     = *(ushort4*)&u[0];
  *(ushort4*)(dst + e + 4) = *(ushort4*)&u[4];
}

// ---------- software grid barrier (device-scope; all blocks co-resident) ---------------
__device__ inline void gridbar(unsigned* bar, unsigned target) {
  __syncthreads();
  if (threadIdx.x == 0) {
    __threadfence();   // release: make this block's stores visible device-wide
    __hip_atomic_fetch_add(bar, 1u, __ATOMIC_ACQ_REL, __HIP_MEMORY_SCOPE_AGENT);
    while (__hip_atomic_load(bar, __ATOMIC_ACQUIRE, __HIP_MEMORY_SCOPE_AGENT) < target) {}
  }
  __syncthreads();
  __threadfence();     // acquire: invalidate caches before reading others' stores
}

// ---------- 64x64 bf16 MFMA tile (BK=64, XOR chunk swizzle, RELU, bf16 out) ------------
__device__ __forceinline__ void tile_gemm64(
    const ushort* __restrict__ A, const ushort* __restrict__ W,
    const float* __restrict__ bias, ushort* __restrict__ Ch,
    int N, int Kd, int row0, int col0, ushort* As, ushort* Bs)
{
  const int tid = threadIdx.x, lane = tid & 63, wave = tid >> 6;
  const int waveM = wave >> 1, waveN = wave & 1;
  const int fm = lane & 15, qq = lane >> 4;
  const int srow = lane >> 3, qslot = lane & 7;

  f4_t acc[2][2];
#pragma unroll
  for (int i = 0; i < 2; i++)
#pragma unroll
    for (int j = 0; j < 2; j++) acc[i][j] = (f4_t){0.f, 0.f, 0.f, 0.f};

  for (int kt = 0; kt < Kd; kt += 64) {
#pragma unroll
    for (int p = 0; p < 2; p++) {
      int rb = p * 32 + wave * 8;
      int r = rb + srow;
      int q = (qslot - r) & 7;
      async16(A + (size_t)(row0 + r) * Kd + kt + q * 8, &As[rb * 64]);
    }
#pragma unroll
    for (int p = 0; p < 2; p++) {
      int rb = p * 32 + wave * 8;
      int r = rb + srow;
      int q = (qslot - r) & 7;
      async16(W + (size_t)(col0 + r) * Kd + kt + q * 8, &Bs[rb * 64]);
    }
    __syncthreads();
#pragma unroll
    for (int t = 0; t < 2; t++) {
      bf8_t af[2], bf[2];
#pragma unroll
      for (int i = 0; i < 2; i++) {
        int r = waveM * 32 + i * 16 + fm;
        int slot = ((t * 4 + qq) + r) & 7;
        af[i] = *(const bf8_t*)&As[r * 64 + slot * 8];
      }
#pragma unroll
      for (int j = 0; j < 2; j++) {
        int r = waveN * 32 + j * 16 + fm;
        int slot = ((t * 4 + qq) + r) & 7;
        bf[j] = *(const bf8_t*)&Bs[r * 64 + slot * 8];
      }
#pragma unroll
      for (int i = 0; i < 2; i++)
#pragma unroll
        for (int j = 0; j < 2; j++)
          acc[i][j] = __builtin_amdgcn_mfma_f32_16x16x32_bf16(af[i], bf[j], acc[i][j], 0, 0, 0);
    }
    __syncthreads();
  }

#pragma unroll
  for (int j = 0; j < 2; j++) {
    int col = col0 + waveN * 32 + j * 16 + fm;
    float bv = bias[col];
#pragma unroll
    for (int i = 0; i < 2; i++) {
      int rbase = row0 + waveM * 32 + i * 16 + qq * 4;
#pragma unroll
      for (int r = 0; r < 4; r++) {
        float t = fmaxf(acc[i][j][r] + bv, 0.0f);
        Ch[(size_t)(rbase + r) * N + col] = f2b(t);
      }
    }
  }
}

// ---------- fused 3-layer MLP: 128 blocks, grid barrier between layers -----------------
__global__ __launch_bounds__(256) void mlp3(
    const ushort* __restrict__ xb,
    const ushort* __restrict__ w0b, const float* __restrict__ b0,
    const ushort* __restrict__ w1b, const float* __restrict__ b1,
    const ushort* __restrict__ w2b, const float* __restrict__ b2,
    ushort* __restrict__ h0, ushort* __restrict__ h1, ushort* __restrict__ h2,
    unsigned* __restrict__ bar)
{
  __shared__ ushort As[64 * 64];
  __shared__ ushort Bs[64 * 64];
  const int row0 = (blockIdx.x >> 3) * 64;      // 16 M-tiles
  const int col0 = (blockIdx.x & 7) * 64;       // 8 N-tiles

  tile_gemm64(xb, w0b, b0, h0, Hh, Dd, row0, col0, As, Bs);
  gridbar(bar, 128);
  tile_gemm64(h0, w1b, b1, h1, Hh, Hh, row0, col0, As, Bs);
  gridbar(bar, 256);
  tile_gemm64(h1, w2b, b2, h2, Hh, Hh, row0, col0, As, Bs);
}

// ---------- big bf16 MFMA GEMM (128x128 tile), fp32 out --------------------------------
__global__ __launch_bounds__(256) void gemm_big(
    const ushort* __restrict__ A, const ushort* __restrict__ W,
    const float* __restrict__ bias, float* __restrict__ Cf,
    int M, int N, int Kd)
{
  __shared__ ushort As[128 * 64];
  __shared__ ushort Bs[128 * 64];
  const int tid = threadIdx.x, lane = tid & 63, wave = tid >> 6;
  const int waveM = wave >> 1, waveN = wave & 1;
  const int row0 = blockIdx.y * 128, col0 = blockIdx.x * 128;
  const int fm = lane & 15, qq = lane >> 4;
  const int srow = lane >> 3, qslot = lane & 7;

  f4_t acc[4][4];
#pragma unroll
  for (int i = 0; i < 4; i++)
#pragma unroll
    for (int j = 0; j < 4; j++) acc[i][j] = (f4_t){0.f, 0.f, 0.f, 0.f};

  for (int kt = 0; kt < Kd; kt += 64) {
#pragma unroll
    for (int p = 0; p < 4; p++) {
      int rb = p * 32 + wave * 8;
      int r = rb + srow;
      int q = (qslot - r) & 7;
      async16(A + (size_t)(row0 + r) * Kd + kt + q * 8, &As[rb * 64]);
    }
#pragma unroll
    for (int p = 0; p < 4; p++) {
      int rb = p * 32 + wave * 8;
      int r = rb + srow;
      int q = (qslot - r) & 7;
      async16(W + (size_t)(col0 + r) * Kd + kt + q * 8, &Bs[rb * 64]);
    }
    __syncthreads();
#pragma unroll
    for (int t = 0; t < 2; t++) {
      bf8_t af[4], bf[4];
#pragma unroll
      for (int i = 0; i < 4; i++) {
        int r = waveM * 64 + i * 16 + fm;
        int slot = ((t * 4 + qq) + r) & 7;
        af[i] = *(const bf8_t*)&As[r * 64 + slot * 8];
      }
#pragma unroll
      for (int j = 0; j < 4; j++) {
        int r = waveN * 64 + j * 16 + fm;
        int slot = ((t * 4 + qq) + r) & 7;
        bf[j] = *(const bf8_t*)&Bs[r * 64 + slot * 8];
      }
#pragma unroll
      for (int i = 0; i < 4; i++)
#pragma unroll
        for (int j = 0; j < 4; j++)
          acc[i][j] = __builtin_amdgcn_mfma_f32_16x16x32_bf16(af[i], bf[j], acc[i][j], 0, 0, 0);
    }
    __syncthreads();
  }

#pragma unroll
  for (int j = 0; j < 4; j++) {
    int col = col0 + waveN * 64 + j * 16 + fm;
    float bv = bias[col];
#pragma unroll
    for (int i = 0; i < 4; i++) {
      int rbase = row0 + waveM * 64 + i * 16 + qq * 4;
#pragma unroll
      for (int r = 0; r < 4; r++)
        Cf[(size_t)(rbase + r) * N + col] = acc[i][j][r] + bv;
    }
  }
}

// ---------------- chain: segmented scan over the 4x4 log-semiring ----------------------
__global__ __launch_bounds__(256) void chain2(
    const float* __restrict__ x, const float* __restrict__ theta,
    const float* __restrict__ lpa, float* __restrict__ logp)
{
  const int b = blockIdx.x;
  const int tid = threadIdx.x;
  const int seg = tid >> 4, e = tid & 15;
  const int i = e >> 2, jj = e & 3;
  const int base = (tid & 63) & ~15;
  const float C0 = 0.91893853320467274178f;     // 0.5*log(2*pi)
  const float* th = theta + (size_t)b * NOUT;
  const float* xb = x + (size_t)b * Dd;
  __shared__ float Ts[16][16];

  const int d0 = 1 + seg * 16;
  const int d1 = min(d0 + 16, Dd - 1);

  auto stepm = [&](int d) -> float {
    float mu = th[d * 32 + e];
    float ls = th[d * 32 + 16 + e];
    float s  = __expf(ls) + 0.01f;
    float z  = (xb[d] - mu) * __builtin_amdgcn_rcpf(s);
    return -0.5f * z * z - __logf(s) - C0 + lpa[d * 4 + jj];
  };

  float T = stepm(d0);
  for (int d = d0 + 1; d < d1; d++) {
    float m_ = stepm(d);
    float v0 = __shfl(T, base + i * 4 + 0) + __shfl(m_, base + 0 * 4 + jj);
    float v1 = __shfl(T, base + i * 4 + 1) + __shfl(m_, base + 1 * 4 + jj);
    float v2 = __shfl(T, base + i * 4 + 2) + __shfl(m_, base + 2 * 4 + jj);
    float v3 = __shfl(T, base + i * 4 + 3) + __shfl(m_, base + 3 * 4 + jj);
    float mx = fmaxf(fmaxf(v0, v1), fmaxf(v2, v3));
    float s  = __expf(v0 - mx) + __expf(v1 - mx) + __expf(v2 - mx) + __expf(v3 - mx);
    T = mx + __logf(s);
  }
  Ts[seg][e] = T;
  __syncthreads();

  if (tid < 4) {
    const int j = tid;
    float mu = th[j], ls = th[16 + j];
    float s = __expf(ls) + 0.01f;
    float z = (xb[0] - mu) * __builtin_amdgcn_rcpf(s);
    float carry = -0.5f * z * z - __logf(s) - C0 + lpa[j];
#pragma unroll 1
    for (int sg = 0; sg < 16; sg++) {
      float c0 = __shfl(carry, 0);
      float c1 = __shfl(carry, 1);
      float c2 = __shfl(carry, 2);
      float c3 = __shfl(carry, 3);
      float v0 = c0 + Ts[sg][0 * 4 + j];
      float v1 = c1 + Ts[sg][1 * 4 + j];
      float v2 = c2 + Ts[sg][2 * 4 + j];
      float v3 = c3 + Ts[sg][3 * 4 + j];
      float mx = fmaxf(fmaxf(v0, v1), fmaxf(v2, v3));
      float ss = __expf(v0 - mx) + __expf(v1 - mx) + __expf(v2 - mx) + __expf(v3 - mx);
      carry = mx + __logf(ss);
    }
    float mu2 = th[255 * 32 + j * 4], ls2 = th[255 * 32 + 16 + j * 4];
    float s2 = __expf(ls2) + 0.01f;
    float z2 = (xb[255] - mu2) * __builtin_amdgcn_rcpf(s2);
    float v = carry - 0.5f * z2 * z2 - __logf(s2) - C0;
    float mx = fmaxf(v, __shfl_xor(v, 1));
    mx = fmaxf(mx, __shfl_xor(mx, 2));
    float ee = __expf(v - mx);
    ee += __shfl_xor(ee, 1);
    ee += __shfl_xor(ee, 2);
    if (j == 0) logp[b] = mx + __logf(ee);
  }
}

extern "C" void kernel_launch(void* const* d_in, const int* in_sizes, int n_in,
                              void* d_out, int out_size, void* d_ws, size_t ws_size,
                              hipStream_t stream)
{
  const float* x    = (const float*)d_in[0];
  const float* W0   = (const float*)d_in[1];
  const float* b0   = (const float*)d_in[2];
  const float* W1   = (const float*)d_in[3];
  const float* b1   = (const float*)d_in[4];
  const float* W2   = (const float*)d_in[5];
  const float* b2   = (const float*)d_in[6];
  const float* Wout = (const float*)d_in[7];
  const float* bout = (const float*)d_in[8];
  const float* ulpa = (const float*)d_in[9];

  float* out   = (float*)d_out;
  float* logp  = out;               // (B,1,1)
  float* theta = out + Bsz;         // (B,D,2,A,A) fp32

  ushort* ws    = (ushort*)d_ws;
  ushort* xb    = ws;                       // 262144
  ushort* w0b   = xb + 262144;              // 131072
  ushort* w1b   = w0b + 131072;             // 262144
  ushort* w2b   = w1b + 262144;             // 262144
  ushort* woutb = w2b + 262144;             // 4194304
  ushort* h0    = woutb + 4194304;          // 524288
  ushort* h1    = h0 + 524288;              // 524288
  ushort* h2    = h1 + 524288;              // 524288
  float*  lpa   = (float*)(h2 + 524288);    // 1020 floats
  unsigned* bar = (unsigned*)(lpa + 1024);  // 16 uints (zeroed by prep)

  prep<<<2497, 256, 0, stream>>>(x, W0, W1, W2, Wout, ulpa,
                                 xb, w0b, w1b, w2b, woutb, lpa, bar);
  mlp3<<<128, 256, 0, stream>>>(xb, w0b, b0, w1b, b1, w2b, b2, h0, h1, h2, bar);
  gemm_big<<<dim3(NOUT / 128, Bsz / 128), 256, 0, stream>>>(h2, woutb, bout, theta, Bsz, NOUT, Hh);
  chain2<<<Bsz, 256, 0, stream>>>(x, theta, lpa, logp);
}

// Round 5
// 138.047 us; speedup vs baseline: 1.2058x; 1.2058x over previous
//
#include <hip/hip_runtime.h>
#include <math.h>

#define Bsz 1024
#define Dd  256
#define Hh  512
#define NOUT 8192       // D*K, K=32

typedef __attribute__((ext_vector_type(8))) short bf8_t;   // 8 bf16 (4 VGPRs)
typedef __attribute__((ext_vector_type(4))) float f4_t;    // 4 fp32

__device__ inline ushort f2b(float f) {
  union { float f; unsigned u; } c; c.f = f;
  unsigned r = c.u + 0x7fffu + ((c.u >> 16) & 1u);   // RNE
  return (ushort)(r >> 16);
}

__device__ inline void async16(const ushort* g, ushort* l) {
  __builtin_amdgcn_global_load_lds((const __attribute__((address_space(1))) void*)g,
                                   (__attribute__((address_space(3))) void*)l, 16, 0, 0);
}

__device__ inline int mod255(int v) {   // valid for v in [0, 765)
  if (v >= 510) return v - 510;
  if (v >= 255) return v - 255;
  return v;
}

// ---------- prep: fp32 -> bf16 (+mask) for x, W0, W1, W2, Wout; block 2496 does lpa ----
__global__ __launch_bounds__(256) void prep(
    const float* __restrict__ x,  const float* __restrict__ W0,
    const float* __restrict__ W1, const float* __restrict__ W2,
    const float* __restrict__ Wout, const float* __restrict__ ulpa,
    ushort* __restrict__ xb, ushort* __restrict__ w0b, ushort* __restrict__ w1b,
    ushort* __restrict__ w2b, ushort* __restrict__ woutb,
    float* __restrict__ lpa)
{
  const int blk = blockIdx.x, tid = threadIdx.x;
  if (blk == 2496) {
    if (tid < Dd - 1) {
      float v0 = ulpa[tid * 4 + 0], v1 = ulpa[tid * 4 + 1];
      float v2 = ulpa[tid * 4 + 2], v3 = ulpa[tid * 4 + 3];
      float m = fmaxf(fmaxf(v0, v1), fmaxf(v2, v3));
      float s = __expf(v0 - m) + __expf(v1 - m) + __expf(v2 - m) + __expf(v3 - m);
      float l = m + __logf(s);
      lpa[tid * 4 + 0] = v0 - l;
      lpa[tid * 4 + 1] = v1 - l;
      lpa[tid * 4 + 2] = v2 - l;
      lpa[tid * 4 + 3] = v3 - l;
    }
    return;
  }
  const float* src; ushort* dst; int lb, mode;
  if (blk < 128)      { src = x;    dst = xb;    lb = blk;       mode = 0; }
  else if (blk < 192) { src = W0;   dst = w0b;   lb = blk - 128; mode = 1; }
  else if (blk < 320) { src = W1;   dst = w1b;   lb = blk - 192; mode = 2; }
  else if (blk < 448) { src = W2;   dst = w2b;   lb = blk - 320; mode = 2; }
  else                { src = Wout; dst = woutb; lb = blk - 448; mode = 3; }

  const int e = lb * 2048 + tid * 8;
  float4 v0 = *(const float4*)(src + e);
  float4 v1 = *(const float4*)(src + e + 4);
  float vv[8] = {v0.x, v0.y, v0.z, v0.w, v1.x, v1.y, v1.z, v1.w};
  ushort u[8];
  if (mode == 0) {
#pragma unroll
    for (int i = 0; i < 8; i++) u[i] = f2b(vv[i]);
  } else if (mode == 1) {            // Kd=256: (n%255) >= k
    int n = e >> 8, k0 = e & 255, nd = mod255(n);
#pragma unroll
    for (int i = 0; i < 8; i++) u[i] = (nd >= k0 + i) ? f2b(vv[i]) : (ushort)0;
  } else if (mode == 2) {            // Kd=512: (n%255) >= (k%255)
    int n = e >> 9, k0 = e & 511, nd = mod255(n);
#pragma unroll
    for (int i = 0; i < 8; i++) u[i] = (nd >= mod255(k0 + i)) ? f2b(vv[i]) : (ushort)0;
  } else {                           // Kd=512: (n>>5)-1 >= (k%255)
    int n = e >> 9, k0 = e & 511, nd = (n >> 5) - 1;
#pragma unroll
    for (int i = 0; i < 8; i++) u[i] = (nd >= mod255(k0 + i)) ? f2b(vv[i]) : (ushort)0;
  }
  *(ushort4*)(dst + e)     = *(ushort4*)&u[0];
  *(ushort4*)(dst + e + 4) = *(ushort4*)&u[4];
}

// ---------- small layer GEMM: 64x32 tile, 256 blocks (1/CU), RELU, bf16 out ------------
// C[1024, 512] = relu(A[1024,KD] @ W[512,KD]^T + bias); all bf16, W pre-masked.
template<int KD>
__global__ __launch_bounds__(256) void gemm_s(
    const ushort* __restrict__ A, const ushort* __restrict__ W,
    const float* __restrict__ bias, ushort* __restrict__ Ch)
{
  __shared__ ushort As[64 * 64];
  __shared__ ushort Bs[32 * 64];
  const int tid = threadIdx.x, lane = tid & 63, wave = tid >> 6;
  const int row0 = blockIdx.y * 64, col0 = blockIdx.x * 32;
  const int fm = lane & 15, qq = lane >> 4;
  const int srow = lane >> 3, qslot = lane & 7;

  f4_t acc[2];
  acc[0] = (f4_t){0.f, 0.f, 0.f, 0.f};
  acc[1] = (f4_t){0.f, 0.f, 0.f, 0.f};

  for (int kt = 0; kt < KD; kt += 64) {
#pragma unroll
    for (int a = 0; a < 2; a++) {                 // A: 64 rows = 8 instrs, 2/wave
      int rb = wave * 16 + a * 8;
      int r = rb + srow;
      int q = (qslot - r) & 7;
      async16(A + (size_t)(row0 + r) * KD + kt + q * 8, &As[rb * 64]);
    }
    {                                             // B: 32 rows = 4 instrs, 1/wave
      int rb = wave * 8;
      int r = rb + srow;
      int q = (qslot - r) & 7;
      async16(W + (size_t)(col0 + r) * KD + kt + q * 8, &Bs[rb * 64]);
    }
    __syncthreads();
#pragma unroll
    for (int t = 0; t < 2; t++) {
      int ra = wave * 16 + fm;
      int slota = ((t * 4 + qq) + ra) & 7;
      bf8_t af = *(const bf8_t*)&As[ra * 64 + slota * 8];
#pragma unroll
      for (int j = 0; j < 2; j++) {
        int rb = j * 16 + fm;
        int slot = ((t * 4 + qq) + rb) & 7;
        bf8_t bf = *(const bf8_t*)&Bs[rb * 64 + slot * 8];
        acc[j] = __builtin_amdgcn_mfma_f32_16x16x32_bf16(af, bf, acc[j], 0, 0, 0);
      }
    }
    __syncthreads();
  }

#pragma unroll
  for (int j = 0; j < 2; j++) {
    int col = col0 + j * 16 + fm;
    float bv = bias[col];
    int rbase = row0 + wave * 16 + qq * 4;
#pragma unroll
    for (int r = 0; r < 4; r++) {
      float t = fmaxf(acc[j][r] + bv, 0.0f);
      Ch[(size_t)(rbase + r) * Hh + col] = f2b(t);
    }
  }
}

// ---------- big bf16 MFMA GEMM (128x128 tile), fp32 out --------------------------------
__global__ __launch_bounds__(256) void gemm_big(
    const ushort* __restrict__ A, const ushort* __restrict__ W,
    const float* __restrict__ bias, float* __restrict__ Cf,
    int M, int N, int Kd)
{
  __shared__ ushort As[128 * 64];
  __shared__ ushort Bs[128 * 64];
  const int tid = threadIdx.x, lane = tid & 63, wave = tid >> 6;
  const int waveM = wave >> 1, waveN = wave & 1;
  const int row0 = blockIdx.y * 128, col0 = blockIdx.x * 128;
  const int fm = lane & 15, qq = lane >> 4;
  const int srow = lane >> 3, qslot = lane & 7;

  f4_t acc[4][4];
#pragma unroll
  for (int i = 0; i < 4; i++)
#pragma unroll
    for (int j = 0; j < 4; j++) acc[i][j] = (f4_t){0.f, 0.f, 0.f, 0.f};

  for (int kt = 0; kt < Kd; kt += 64) {
#pragma unroll
    for (int p = 0; p < 4; p++) {
      int rb = p * 32 + wave * 8;
      int r = rb + srow;
      int q = (qslot - r) & 7;
      async16(A + (size_t)(row0 + r) * Kd + kt + q * 8, &As[rb * 64]);
    }
#pragma unroll
    for (int p = 0; p < 4; p++) {
      int rb = p * 32 + wave * 8;
      int r = rb + srow;
      int q = (qslot - r) & 7;
      async16(W + (size_t)(col0 + r) * Kd + kt + q * 8, &Bs[rb * 64]);
    }
    __syncthreads();
#pragma unroll
    for (int t = 0; t < 2; t++) {
      bf8_t af[4], bf[4];
#pragma unroll
      for (int i = 0; i < 4; i++) {
        int r = waveM * 64 + i * 16 + fm;
        int slot = ((t * 4 + qq) + r) & 7;
        af[i] = *(const bf8_t*)&As[r * 64 + slot * 8];
      }
#pragma unroll
      for (int j = 0; j < 4; j++) {
        int r = waveN * 64 + j * 16 + fm;
        int slot = ((t * 4 + qq) + r) & 7;
        bf[j] = *(const bf8_t*)&Bs[r * 64 + slot * 8];
      }
#pragma unroll
      for (int i = 0; i < 4; i++)
#pragma unroll
        for (int j = 0; j < 4; j++)
          acc[i][j] = __builtin_amdgcn_mfma_f32_16x16x32_bf16(af[i], bf[j], acc[i][j], 0, 0, 0);
    }
    __syncthreads();
  }

#pragma unroll
  for (int j = 0; j < 4; j++) {
    int col = col0 + waveN * 64 + j * 16 + fm;
    float bv = bias[col];
#pragma unroll
    for (int i = 0; i < 4; i++) {
      int rbase = row0 + waveM * 64 + i * 16 + qq * 4;
#pragma unroll
      for (int r = 0; r < 4; r++)
        Cf[(size_t)(rbase + r) * N + col] = acc[i][j][r] + bv;
    }
  }
}

// ---------------- chain: segmented scan over the 4x4 log-semiring ----------------------
__global__ __launch_bounds__(256) void chain2(
    const float* __restrict__ x, const float* __restrict__ theta,
    const float* __restrict__ lpa, float* __restrict__ logp)
{
  const int b = blockIdx.x;
  const int tid = threadIdx.x;
  const int seg = tid >> 4, e = tid & 15;
  const int i = e >> 2, jj = e & 3;
  const int base = (tid & 63) & ~15;
  const float C0 = 0.91893853320467274178f;     // 0.5*log(2*pi)
  const float* th = theta + (size_t)b * NOUT;
  const float* xb = x + (size_t)b * Dd;
  __shared__ float Ts[16][16];

  const int d0 = 1 + seg * 16;
  const int d1 = min(d0 + 16, Dd - 1);

  auto stepm = [&](int d) -> float {
    float mu = th[d * 32 + e];
    float ls = th[d * 32 + 16 + e];
    float s  = __expf(ls) + 0.01f;
    float z  = (xb[d] - mu) * __builtin_amdgcn_rcpf(s);
    return -0.5f * z * z - __logf(s) - C0 + lpa[d * 4 + jj];
  };

  float T = stepm(d0);
  for (int d = d0 + 1; d < d1; d++) {
    float m_ = stepm(d);
    float v0 = __shfl(T, base + i * 4 + 0) + __shfl(m_, base + 0 * 4 + jj);
    float v1 = __shfl(T, base + i * 4 + 1) + __shfl(m_, base + 1 * 4 + jj);
    float v2 = __shfl(T, base + i * 4 + 2) + __shfl(m_, base + 2 * 4 + jj);
    float v3 = __shfl(T, base + i * 4 + 3) + __shfl(m_, base + 3 * 4 + jj);
    float mx = fmaxf(fmaxf(v0, v1), fmaxf(v2, v3));
    float s  = __expf(v0 - mx) + __expf(v1 - mx) + __expf(v2 - mx) + __expf(v3 - mx);
    T = mx + __logf(s);
  }
  Ts[seg][e] = T;
  __syncthreads();

  if (tid < 4) {
    const int j = tid;
    float mu = th[j], ls = th[16 + j];
    float s = __expf(ls) + 0.01f;
    float z = (xb[0] - mu) * __builtin_amdgcn_rcpf(s);
    float carry = -0.5f * z * z - __logf(s) - C0 + lpa[j];
#pragma unroll 1
    for (int sg = 0; sg < 16; sg++) {
      float c0 = __shfl(carry, 0);
      float c1 = __shfl(carry, 1);
      float c2 = __shfl(carry, 2);
      float c3 = __shfl(carry, 3);
      float v0 = c0 + Ts[sg][0 * 4 + j];
      float v1 = c1 + Ts[sg][1 * 4 + j];
      float v2 = c2 + Ts[sg][2 * 4 + j];
      float v3 = c3 + Ts[sg][3 * 4 + j];
      float mx = fmaxf(fmaxf(v0, v1), fmaxf(v2, v3));
      float ss = __expf(v0 - mx) + __expf(v1 - mx) + __expf(v2 - mx) + __expf(v3 - mx);
      carry = mx + __logf(ss);
    }
    float mu2 = th[255 * 32 + j * 4], ls2 = th[255 * 32 + 16 + j * 4];
    float s2 = __expf(ls2) + 0.01f;
    float z2 = (xb[255] - mu2) * __builtin_amdgcn_rcpf(s2);
    float v = carry - 0.5f * z2 * z2 - __logf(s2) - C0;
    float mx = fmaxf(v, __shfl_xor(v, 1));
    mx = fmaxf(mx, __shfl_xor(mx, 2));
    float ee = __expf(v - mx);
    ee += __shfl_xor(ee, 1);
    ee += __shfl_xor(ee, 2);
    if (j == 0) logp[b] = mx + __logf(ee);
  }
}

extern "C" void kernel_launch(void* const* d_in, const int* in_sizes, int n_in,
                              void* d_out, int out_size, void* d_ws, size_t ws_size,
                              hipStream_t stream)
{
  const float* x    = (const float*)d_in[0];
  const float* W0   = (const float*)d_in[1];
  const float* b0   = (const float*)d_in[2];
  const float* W1   = (const float*)d_in[3];
  const float* b1   = (const float*)d_in[4];
  const float* W2   = (const float*)d_in[5];
  const float* b2   = (const float*)d_in[6];
  const float* Wout = (const float*)d_in[7];
  const float* bout = (const float*)d_in[8];
  const float* ulpa = (const float*)d_in[9];

  float* out   = (float*)d_out;
  float* logp  = out;               // (B,1,1)
  float* theta = out + Bsz;         // (B,D,2,A,A) fp32

  ushort* ws    = (ushort*)d_ws;
  ushort* xb    = ws;                       // 262144
  ushort* w0b   = xb + 262144;              // 131072
  ushort* w1b   = w0b + 131072;             // 262144
  ushort* w2b   = w1b + 262144;             // 262144
  ushort* woutb = w2b + 262144;             // 4194304
  ushort* h0    = woutb + 4194304;          // 524288
  ushort* h1    = h0 + 524288;              // 524288
  ushort* h2    = h1 + 524288;              // 524288
  float*  lpa   = (float*)(h2 + 524288);    // 1020 floats

  prep<<<2497, 256, 0, stream>>>(x, W0, W1, W2, Wout, ulpa,
                                 xb, w0b, w1b, w2b, woutb, lpa);
  gemm_s<Dd><<<dim3(16, 16), 256, 0, stream>>>(xb, w0b, b0, h0);
  gemm_s<Hh><<<dim3(16, 16), 256, 0, stream>>>(h0, w1b, b1, h1);
  gemm_s<Hh><<<dim3(16, 16), 256, 0, stream>>>(h1, w2b, b2, h2);
  gemm_big<<<dim3(NOUT / 128, Bsz / 128), 256, 0, stream>>>(h2, woutb, bout, theta, Bsz, NOUT, Hh);
  chain2<<<Bsz, 256, 0, stream>>>(x, theta, lpa, logp);
}